// Round 7
// baseline (152.863 us; speedup 1.0000x reference)
//
#include <hip/hip_runtime.h>
#include <stdint.h>

#define HH 512
#define WW 512
#define WPR 8                 // u64 words per row (512 bits)
#define NWORDS (HH * WPR)     // 4096 words per image
#define NB 16                 // batch
#define NMASK (2 * NB)        // 32 packed masks (16 pred + 16 true)

#define NP 4                  // blocks (parts) per mask
#define PR (HH / NP)          // 128 rows per part
#define MAXIT 300

// ws layout (bytes):
//   bits : u64[NMASK*NWORDS]            @ 0        (1 MB)
//   sync : int[SYNC_INTS]               @ 1 MB     (cnt[65] @0, bar[32] @72, chg[32*MAXIT] @104)
//   halo : u64[2][NMASK][NP][2][8]      @ 1 MB + 40960
#define SYNC_OFF   (NMASK * NWORDS * 8)
#define CNT_BASE   0
#define BAR_BASE   72
#define CHG_BASE   104
#define SYNC_INTS  (CHG_BASE + NMASK * MAXIT)
#define HALO_OFF   (SYNC_OFF + 40960)

typedef unsigned long long u64;

__device__ __forceinline__ u64 ldh(const u64* M, int lr, int c) {
    return (c < 0 || c >= WPR) ? 0ULL : M[lr * WPR + c];   // rows always valid
}

// One Zhang-Suen sub-step for LDS word (lr,c); lr in [1,128], halo rows 0/129.
__device__ __forceinline__ u64 zs_word(const u64* M, int lr, int c, int step) {
    u64 nm = ldh(M, lr - 1, c - 1), nc = ldh(M, lr - 1, c), np = ldh(M, lr - 1, c + 1);
    u64 cm = ldh(M, lr,     c - 1), cc = ldh(M, lr,     c), cp = ldh(M, lr,     c + 1);
    u64 sm = ldh(M, lr + 1, c - 1), sc = ldh(M, lr + 1, c), sp = ldh(M, lr + 1, c + 1);

    u64 P2 = nc;
    u64 P3 = (nc >> 1) | (np << 63);
    u64 P4 = (cc >> 1) | (cp << 63);
    u64 P5 = (sc >> 1) | (sp << 63);
    u64 P6 = sc;
    u64 P7 = (sc << 1) | (sm >> 63);
    u64 P8 = (cc << 1) | (cm >> 63);
    u64 P9 = (nc << 1) | (nm >> 63);

    u64 ab = P2 ^ P3;
    u64 s1 = ab ^ P4, c1 = (P2 & P3) | (ab & P4);
    u64 de = P5 ^ P6;
    u64 s2 = de ^ P7, c2 = (P5 & P6) | (de & P7);
    u64 s3 = P8 ^ P9, c3 = P8 & P9;
    u64 gh = s1 ^ s2;
    u64 b0 = gh ^ s3, c4 = (s1 & s2) | (gh & s3);
    u64 ij = c1 ^ c2;
    u64 s4 = ij ^ c3, c5 = (c1 & c2) | (ij & c3);
    u64 b1 = s4 ^ c4, c6 = s4 & c4;
    u64 b2 = c5 ^ c6, b3 = c5 & c6;

    u64 Bge2 = b1 | b2 | b3;
    u64 Ble6 = ~(b3 | (b2 & b1 & b0));

    u64 a1, a2, t;
    t = ~P2 & P3; a1 = t; a2 = 0ULL;
    t = ~P3 & P4; a2 |= a1 & t; a1 |= t;
    t = ~P4 & P5; a2 |= a1 & t; a1 |= t;
    t = ~P5 & P6; a2 |= a1 & t; a1 |= t;
    t = ~P6 & P7; a2 |= a1 & t; a1 |= t;
    t = ~P7 & P8; a2 |= a1 & t; a1 |= t;
    t = ~P8 & P9; a2 |= a1 & t; a1 |= t;
    t = ~P9 & P2; a2 |= a1 & t; a1 |= t;
    u64 Aeq1 = a1 & ~a2;

    u64 sccond;
    if (step == 0) sccond = ~(P2 & P4 & P6) & ~(P4 & P6 & P8);
    else           sccond = ~(P2 & P4 & P8) & ~(P2 & P6 & P8);

    return cc & ~(Bge2 & Ble6 & Aeq1 & sccond);
}

// spread 16 bits so bit j lands at position 4j
__device__ __forceinline__ u64 spread4(u64 x) {
    x &= 0xFFFFULL;
    x = (x | (x << 24)) & 0x000000FF000000FFULL;
    x = (x | (x << 12)) & 0x000F000F000F000FULL;
    x = (x | (x << 6))  & 0x0303030303030303ULL;
    x = (x | (x << 3))  & 0x1111111111111111ULL;
    return x;
}

// ---------------- pack: coalesced float4 + ballot + Morton repack ----------
__global__ __launch_bounds__(256)
void pack_kernel(const float* __restrict__ y_pred,
                 const float* __restrict__ y_true,
                 u64* __restrict__ bits,
                 int* __restrict__ sync) {
    int gid = blockIdx.x * 256 + threadIdx.x;
    if (gid < SYNC_INTS) sync[gid] = 0;               // cnt + bar + chg zeroed
    int wid = gid >> 6;                               // wave id 0..8191
    int lane = threadIdx.x & 63;
    int w = lane & 3;
    int sh = w * 16;
    #pragma unroll
    for (int it = 0; it < 4; ++it) {
        int ch = wid * 4 + it;                        // chunk 0..32767
        int f4 = ch * 64 + lane;
        int img = f4 >> 16;                           // 65536 float4 per image
        const float* src = (img < NB) ? y_pred + (size_t)img * (HH * WW)
                                      : y_true + (size_t)(img - NB) * (HH * WW);
        float4 a = ((const float4*)src)[f4 & 65535];  // coalesced 1KB/wave
        u64 B0 = __ballot(a.x > 0.5f);
        u64 B1 = __ballot(a.y > 0.5f);
        u64 B2 = __ballot(a.z > 0.5f);
        u64 B3 = __ballot(a.w > 0.5f);
        u64 word = spread4(B0 >> sh)
                 | (spread4(B1 >> sh) << 1)
                 | (spread4(B2 >> sh) << 2)
                 | (spread4(B3 >> sh) << 3);
        if (lane < 4) bits[ch * 4 + w] = word;
    }
}

// ---------------- skeletonize: NP blocks per mask, atomic halo exchange -----
__global__ __launch_bounds__(1024)
void skel_kernel(u64* __restrict__ bits, int* __restrict__ sync,
                 u64* __restrict__ halo) {
    __shared__ u64 M[(PR + 2) * WPR];       // 130 rows x 8 words
    __shared__ unsigned Cp[PR + 4];         // Cp[lr+1] = change mask of LDS row lr
    __shared__ int s_chg;
    __shared__ int s_bc;

    int bx = blockIdx.x;
    int m = bx >> 2, j = bx & (NP - 1);
    int tid = threadIdx.x;
    int lane = tid & 63;
    u64* mine = bits + (size_t)m * NWORDS;
    int* bar = sync + BAR_BASE + m;
    int* chg = sync + CHG_BASE + m * MAXIT;

    // load 130 rows (128 + halos) from packed global
    for (int i = tid; i < (PR + 2) * WPR; i += 1024) {
        int gr = PR * j - 1 + (i >> 3);
        M[i] = (gr >= 0 && gr < HH) ? mine[gr * WPR + (i & 7)] : 0ULL;
    }
    if (tid < PR + 4) {
        unsigned v = 0;
        if (tid >= 2 && tid <= PR + 1) v = 0x1FEu;          // interior rows dirty
        if (tid == 1) v = (j > 0) ? 0x1FEu : 0u;            // top halo row
        if (tid == PR + 2) v = (j < NP - 1) ? 0x1FEu : 0u;  // bottom halo row
        Cp[tid] = v;
    }
    if (tid == 0) s_chg = 0;

    int lr = (tid >> 3) + 1;       // my LDS row 1..128
    int c = tid & 7;
    int wi = lr * WPR + c;
    int shl = lane & 56;           // row-base lane for ballot byte
    unsigned dl = 0x1FEu;          // my row's last-sub-step change mask

    int s = 0;
    for (int it = 0; it < MAXIT; ++it) {
        for (int step = 0; step < 2; ++step) {
            __syncthreads();       // (A) prior writes + halo imports visible
            unsigned need = ((Cp[lr] | Cp[lr + 1] | Cp[lr + 2]) >> c) & 7u;
            u64 x = 0; bool ch = false;
            if (need) {
                x = zs_word(M, lr, c, step);
                ch = (x != M[wi]);
            }
            u64 bal = __ballot(ch);
            __syncthreads();       // (B) all reads done
            if ((bal >> lane) & 1) M[wi] = x;
            unsigned nb = ((unsigned)((bal >> shl) & 0xFFu)) << 1;
            if ((lane & 7) == 0) Cp[lr + 1] = nb | dl;
            dl = nb;
            if (lane == 0 && bal) atomicOr(&s_chg, 1);
            // halo export: boundary rows always recomputed (forced dirty) -> x valid
            s++;
            int par = s & 1;
            if (j > 0 && lr == 1)
                __hip_atomic_store(&halo[(((size_t)par * NMASK + m) * NP + j) * 16 + c],
                                   x, __ATOMIC_RELAXED, __HIP_MEMORY_SCOPE_AGENT);
            if (j < NP - 1 && lr == PR)
                __hip_atomic_store(&halo[(((size_t)par * NMASK + m) * NP + j) * 16 + 8 + c],
                                   x, __ATOMIC_RELAXED, __HIP_MEMORY_SCOPE_AGENT);
            __syncthreads();       // (C) M/Cp/s_chg + halo stores complete
            if (tid == 0) {
                if (step == 1 && s_chg)
                    __hip_atomic_fetch_or(&chg[it], 1, __ATOMIC_RELAXED,
                                          __HIP_MEMORY_SCOPE_AGENT);
                __hip_atomic_fetch_add(bar, 1, __ATOMIC_RELEASE,
                                       __HIP_MEMORY_SCOPE_AGENT);
                while (__hip_atomic_load(bar, __ATOMIC_ACQUIRE,
                                         __HIP_MEMORY_SCOPE_AGENT) < NP * s)
                    __builtin_amdgcn_s_sleep(1);
            }
            __syncthreads();       // (D) barrier passed
            // halo import for next sub-step (same parity)
            if (j > 0 && tid < 8)
                M[tid] = __hip_atomic_load(
                    &halo[(((size_t)par * NMASK + m) * NP + (j - 1)) * 16 + 8 + tid],
                    __ATOMIC_RELAXED, __HIP_MEMORY_SCOPE_AGENT);
            if (j < NP - 1 && tid >= 8 && tid < 16)
                M[(PR + 1) * WPR + (tid - 8)] = __hip_atomic_load(
                    &halo[(((size_t)par * NMASK + m) * NP + (j + 1)) * 16 + (tid - 8)],
                    __ATOMIC_RELAXED, __HIP_MEMORY_SCOPE_AGENT);
        }
        if (tid == 0) {
            s_bc = __hip_atomic_load(&chg[it], __ATOMIC_RELAXED,
                                     __HIP_MEMORY_SCOPE_AGENT);
            s_chg = 0;
        }
        __syncthreads();           // (E) s_bc visible
        if (s_bc == 0) break;      // uniform across all parts of this mask
    }

    // store my 128 rows back (coalesced)
    mine[j * (PR * WPR) + tid] = M[wi];
}

// ---------------- count: 16 strips/image, 256 blocks, fused final reduce ----
#define STRIPS 16
#define SROWS (HH / STRIPS)   // 32 interior rows per strip
#define SR2 (SROWS + 6)       // + 3-row halo each side
#define CBLOCKS (NB * STRIPS) // 256

// radius-3 disk dilation; strip-local r in [3, 3+SROWS)
__device__ __forceinline__ u64 dil3s(const u64* M, int r, int c) {
    u64 cm = ldh(M, r, c - 1), cc = ldh(M, r, c), cp = ldh(M, r, c + 1);
    u64 h = cc
          | (cc >> 1) | (cp << 63)
          | (cc >> 2) | (cp << 62)
          | (cc >> 3) | (cp << 61)
          | (cc << 1) | (cm >> 63)
          | (cc << 2) | (cm >> 62)
          | (cc << 3) | (cm >> 61);
    u64 um = ldh(M, r - 1, c - 1) | ldh(M, r + 1, c - 1) | ldh(M, r - 2, c - 1) | ldh(M, r + 2, c - 1);
    u64 uc = ldh(M, r - 1, c    ) | ldh(M, r + 1, c    ) | ldh(M, r - 2, c    ) | ldh(M, r + 2, c    );
    u64 up = ldh(M, r - 1, c + 1) | ldh(M, r + 1, c + 1) | ldh(M, r - 2, c + 1) | ldh(M, r + 2, c + 1);
    h |= uc
       | (uc >> 1) | (up << 63)
       | (uc >> 2) | (up << 62)
       | (uc << 1) | (um >> 63)
       | (uc << 2) | (um >> 62);
    h |= ldh(M, r - 3, c) | ldh(M, r + 3, c);
    return h;
}

__global__ __launch_bounds__(256)
void count_kernel(const u64* __restrict__ bits, int* __restrict__ cnt,
                  float* __restrict__ out) {
    __shared__ u64 P[SR2 * WPR];
    __shared__ u64 G[SR2 * WPR];
    __shared__ int acc[4];
    __shared__ int s_last;
    __shared__ int s_cnt[4 * NB];

    int b = blockIdx.x / STRIPS;
    int s = blockIdx.x % STRIPS;
    int tid = threadIdx.x;
    int r0 = s * SROWS - 3;

    const u64* sp = bits + (size_t)b * NWORDS;
    const u64* sg = bits + (size_t)(NB + b) * NWORDS;
    for (int i = tid; i < SR2 * WPR; i += 256) {
        int gr = r0 + (i >> 3);
        bool in = (gr >= 0 && gr < HH);
        int gi = gr * WPR + (i & 7);
        P[i] = in ? sp[gi] : 0ULL;
        G[i] = in ? sg[gi] : 0ULL;
    }
    if (tid < 4) acc[tid] = 0;
    __syncthreads();

    int r = (tid >> 3) + 3, c = tid & 7;
    u64 pw = P[r * WPR + c], gw = G[r * WPR + c];
    int cp  = __popcll(pw);
    int cg  = __popcll(gw);
    int tp  = __popcll(pw & dil3s(G, r, c));
    int fnh = __popcll(gw & dil3s(P, r, c));

    #pragma unroll
    for (int o = 32; o > 0; o >>= 1) {
        cp  += __shfl_down(cp, o);
        cg  += __shfl_down(cg, o);
        tp  += __shfl_down(tp, o);
        fnh += __shfl_down(fnh, o);
    }
    if ((tid & 63) == 0) {
        atomicAdd(&acc[0], cp);
        atomicAdd(&acc[1], cg);
        atomicAdd(&acc[2], tp);
        atomicAdd(&acc[3], fnh);
    }
    __syncthreads();
    if (tid < 4) atomicAdd(&cnt[b * 4 + tid], acc[tid]);

    __threadfence();
    if (tid == 0) {
        int old = atomicAdd(&cnt[4 * NB], 1);
        s_last = (old == CBLOCKS - 1);
    }
    __syncthreads();
    if (!s_last) return;
    __threadfence();
    if (tid < 4 * NB) s_cnt[tid] = atomicAdd(&cnt[tid], 0);
    __syncthreads();
    if (tid < 3) {
        float sum = 0.0f;
        for (int bb = 0; bb < NB; ++bb) {
            float TP = (float)s_cnt[bb * 4 + 2];
            float FP = (float)(s_cnt[bb * 4 + 0] - s_cnt[bb * 4 + 2]);
            float FN = (float)(s_cnt[bb * 4 + 1] - s_cnt[bb * 4 + 3]);
            float v = (tid == 0) ? TP / (TP + FP + 1e-12f)
                    : (tid == 1) ? TP / (TP + FN + 1e-12f)
                                 : TP / (TP + FP + FN + 1e-12f);
            sum += v;
        }
        out[tid] = sum * (1.0f / NB);
    }
}

extern "C" void kernel_launch(void* const* d_in, const int* in_sizes, int n_in,
                              void* d_out, int out_size, void* d_ws, size_t ws_size,
                              hipStream_t stream) {
    (void)in_sizes; (void)n_in; (void)out_size; (void)ws_size;
    const float* y_pred = (const float*)d_in[0];
    const float* y_true = (const float*)d_in[1];
    float* out = (float*)d_out;

    u64* bits = (u64*)d_ws;
    int* sync = (int*)((char*)d_ws + SYNC_OFF);
    u64* halo = (u64*)((char*)d_ws + HALO_OFF);

    hipLaunchKernelGGL(pack_kernel, dim3(2048), dim3(256), 0, stream,
                       y_pred, y_true, bits, sync);
    hipLaunchKernelGGL(skel_kernel, dim3(NMASK * NP), dim3(1024), 0, stream,
                       bits, sync, halo);
    hipLaunchKernelGGL(count_kernel, dim3(CBLOCKS), dim3(256), 0, stream,
                       bits, sync + CNT_BASE, out);
}

// Round 8
// 132.658 us; speedup vs baseline: 1.1523x; 1.1523x over previous
//
#include <hip/hip_runtime.h>
#include <stdint.h>

#define HH 512
#define WW 512
#define WPR 8                 // u64 words per row (512 bits)
#define NWORDS (HH * WPR)     // 4096 words per image
#define NB 16                 // batch
#define NMASK (2 * NB)        // 32 packed masks (16 pred + 16 true)

#define NP 4                  // blocks (parts) per mask
#define PR (HH / NP)          // 128 rows per part
#define MAXIT 300

// ws layout (ints within sync region):
//   cnt[65]              @ int 0     (count kernel counters + done)
//   bar slabs            @ int 64 + m*64   (one 256-B line per mask)
//   chg[m][MAXIT]        @ int CHG_BASE + m*MAXIT  (1200 B/mask, own lines)
#define SYNC_OFF   (NMASK * NWORDS * 8)
#define CNT_BASE   0
#define BAR_BASE   64
#define CHG_BASE   (BAR_BASE + NMASK * 64)
#define SYNC_INTS  (CHG_BASE + NMASK * MAXIT)
#define HALO_OFF   (SYNC_OFF + ((SYNC_INTS * 4 + 255) & ~255))

typedef unsigned long long u64;

__device__ __forceinline__ u64 ldh(const u64* M, int lr, int c) {
    return (c < 0 || c >= WPR) ? 0ULL : M[lr * WPR + c];   // rows always valid
}

// One Zhang-Suen sub-step for LDS word (lr,c); lr in [1,128], halo rows 0/129.
__device__ __forceinline__ u64 zs_word(const u64* M, int lr, int c, int step) {
    u64 nm = ldh(M, lr - 1, c - 1), nc = ldh(M, lr - 1, c), np = ldh(M, lr - 1, c + 1);
    u64 cm = ldh(M, lr,     c - 1), cc = ldh(M, lr,     c), cp = ldh(M, lr,     c + 1);
    u64 sm = ldh(M, lr + 1, c - 1), sc = ldh(M, lr + 1, c), sp = ldh(M, lr + 1, c + 1);

    u64 P2 = nc;
    u64 P3 = (nc >> 1) | (np << 63);
    u64 P4 = (cc >> 1) | (cp << 63);
    u64 P5 = (sc >> 1) | (sp << 63);
    u64 P6 = sc;
    u64 P7 = (sc << 1) | (sm >> 63);
    u64 P8 = (cc << 1) | (cm >> 63);
    u64 P9 = (nc << 1) | (nm >> 63);

    u64 ab = P2 ^ P3;
    u64 s1 = ab ^ P4, c1 = (P2 & P3) | (ab & P4);
    u64 de = P5 ^ P6;
    u64 s2 = de ^ P7, c2 = (P5 & P6) | (de & P7);
    u64 s3 = P8 ^ P9, c3 = P8 & P9;
    u64 gh = s1 ^ s2;
    u64 b0 = gh ^ s3, c4 = (s1 & s2) | (gh & s3);
    u64 ij = c1 ^ c2;
    u64 s4 = ij ^ c3, c5 = (c1 & c2) | (ij & c3);
    u64 b1 = s4 ^ c4, c6 = s4 & c4;
    u64 b2 = c5 ^ c6, b3 = c5 & c6;

    u64 Bge2 = b1 | b2 | b3;
    u64 Ble6 = ~(b3 | (b2 & b1 & b0));

    u64 a1, a2, t;
    t = ~P2 & P3; a1 = t; a2 = 0ULL;
    t = ~P3 & P4; a2 |= a1 & t; a1 |= t;
    t = ~P4 & P5; a2 |= a1 & t; a1 |= t;
    t = ~P5 & P6; a2 |= a1 & t; a1 |= t;
    t = ~P6 & P7; a2 |= a1 & t; a1 |= t;
    t = ~P7 & P8; a2 |= a1 & t; a1 |= t;
    t = ~P8 & P9; a2 |= a1 & t; a1 |= t;
    t = ~P9 & P2; a2 |= a1 & t; a1 |= t;
    u64 Aeq1 = a1 & ~a2;

    u64 sccond;
    if (step == 0) sccond = ~(P2 & P4 & P6) & ~(P4 & P6 & P8);
    else           sccond = ~(P2 & P4 & P8) & ~(P2 & P6 & P8);

    return cc & ~(Bge2 & Ble6 & Aeq1 & sccond);
}

// spread 16 bits so bit j lands at position 4j
__device__ __forceinline__ u64 spread4(u64 x) {
    x &= 0xFFFFULL;
    x = (x | (x << 24)) & 0x000000FF000000FFULL;
    x = (x | (x << 12)) & 0x000F000F000F000FULL;
    x = (x | (x << 6))  & 0x0303030303030303ULL;
    x = (x | (x << 3))  & 0x1111111111111111ULL;
    return x;
}

// ---------------- pack: coalesced float4 + ballot + Morton repack ----------
__global__ __launch_bounds__(256)
void pack_kernel(const float* __restrict__ y_pred,
                 const float* __restrict__ y_true,
                 u64* __restrict__ bits,
                 int* __restrict__ sync) {
    int gid = blockIdx.x * 256 + threadIdx.x;
    if (gid < SYNC_INTS) sync[gid] = 0;               // cnt + bar + chg zeroed
    int wid = gid >> 6;                               // wave id 0..8191
    int lane = threadIdx.x & 63;
    int w = lane & 3;
    int sh = w * 16;
    #pragma unroll
    for (int it = 0; it < 4; ++it) {
        int ch = wid * 4 + it;                        // chunk 0..32767
        int f4 = ch * 64 + lane;
        int img = f4 >> 16;                           // 65536 float4 per image
        const float* src = (img < NB) ? y_pred + (size_t)img * (HH * WW)
                                      : y_true + (size_t)(img - NB) * (HH * WW);
        float4 a = ((const float4*)src)[f4 & 65535];  // coalesced 1KB/wave
        u64 B0 = __ballot(a.x > 0.5f);
        u64 B1 = __ballot(a.y > 0.5f);
        u64 B2 = __ballot(a.z > 0.5f);
        u64 B3 = __ballot(a.w > 0.5f);
        u64 word = spread4(B0 >> sh)
                 | (spread4(B1 >> sh) << 1)
                 | (spread4(B2 >> sh) << 2)
                 | (spread4(B3 >> sh) << 3);
        if (lane < 4) bits[ch * 4 + w] = word;
    }
}

// ---------------- skeletonize: NP blocks per mask, atomic halo exchange -----
// Block mapping: m = bx & 31, j = bx >> 5  ==>  a mask's NP blocks share
// bx % 8, i.e. land on the SAME XCD under round-robin dispatch (perf
// heuristic only; agent-scope atomics keep correctness placement-independent).
__global__ __launch_bounds__(1024)
void skel_kernel(u64* __restrict__ bits, int* __restrict__ sync,
                 u64* __restrict__ halo) {
    __shared__ u64 M[(PR + 2) * WPR];       // 130 rows x 8 words
    __shared__ unsigned Cp[PR + 4];         // Cp[lr+1] = change mask of LDS row lr
    __shared__ int s_chg;
    __shared__ int s_bc;

    int bx = blockIdx.x;
    int m = bx & (NMASK - 1), j = bx >> 5;
    int tid = threadIdx.x;
    int lane = tid & 63;
    u64* mine = bits + (size_t)m * NWORDS;
    int* bar = sync + BAR_BASE + m * 64;    // one 256-B slab per mask
    int* chg = sync + CHG_BASE + m * MAXIT;

    // load 130 rows (128 + halos) from packed global
    for (int i = tid; i < (PR + 2) * WPR; i += 1024) {
        int gr = PR * j - 1 + (i >> 3);
        M[i] = (gr >= 0 && gr < HH) ? mine[gr * WPR + (i & 7)] : 0ULL;
    }
    if (tid < PR + 4) {
        unsigned v = 0;
        if (tid >= 2 && tid <= PR + 1) v = 0x1FEu;          // interior rows dirty
        if (tid == 1) v = (j > 0) ? 0x1FEu : 0u;            // top halo row
        if (tid == PR + 2) v = (j < NP - 1) ? 0x1FEu : 0u;  // bottom halo row
        Cp[tid] = v;
    }
    if (tid == 0) s_chg = 0;

    int lr = (tid >> 3) + 1;       // my LDS row 1..128
    int c = tid & 7;
    int wi = lr * WPR + c;
    int shl = lane & 56;           // row-base lane for ballot byte
    unsigned dl = 0x1FEu;          // my row's last-sub-step change mask

    int s = 0;
    for (int it = 0; it < MAXIT; ++it) {
        for (int step = 0; step < 2; ++step) {
            __syncthreads();       // (A) prior writes + halo imports visible
            unsigned need = ((Cp[lr] | Cp[lr + 1] | Cp[lr + 2]) >> c) & 7u;
            u64 x = 0; bool ch = false;
            if (need) {
                x = zs_word(M, lr, c, step);
                ch = (x != M[wi]);
            }
            u64 bal = __ballot(ch);
            __syncthreads();       // (B) all reads done
            if ((bal >> lane) & 1) M[wi] = x;
            unsigned nb = ((unsigned)((bal >> shl) & 0xFFu)) << 1;
            if ((lane & 7) == 0) Cp[lr + 1] = nb | dl;
            dl = nb;
            if (lane == 0 && bal) atomicOr(&s_chg, 1);
            // halo export: boundary rows always recomputed (forced dirty) -> x valid
            s++;
            int par = s & 1;
            if (j > 0 && lr == 1)
                __hip_atomic_store(&halo[(((size_t)par * NMASK + m) * NP + j) * 16 + c],
                                   x, __ATOMIC_RELAXED, __HIP_MEMORY_SCOPE_AGENT);
            if (j < NP - 1 && lr == PR)
                __hip_atomic_store(&halo[(((size_t)par * NMASK + m) * NP + j) * 16 + 8 + c],
                                   x, __ATOMIC_RELAXED, __HIP_MEMORY_SCOPE_AGENT);
            __syncthreads();       // (C) M/Cp/s_chg + halo stores complete
            if (tid == 0) {
                if (step == 1 && s_chg)
                    __hip_atomic_fetch_or(&chg[it], 1, __ATOMIC_RELAXED,
                                          __HIP_MEMORY_SCOPE_AGENT);
                __hip_atomic_fetch_add(bar, 1, __ATOMIC_RELEASE,
                                       __HIP_MEMORY_SCOPE_AGENT);
                while (__hip_atomic_load(bar, __ATOMIC_ACQUIRE,
                                         __HIP_MEMORY_SCOPE_AGENT) < NP * s)
                    __builtin_amdgcn_s_sleep(1);
            }
            __syncthreads();       // (D) barrier passed
            // halo import for next sub-step (same parity)
            if (j > 0 && tid < 8)
                M[tid] = __hip_atomic_load(
                    &halo[(((size_t)par * NMASK + m) * NP + (j - 1)) * 16 + 8 + tid],
                    __ATOMIC_RELAXED, __HIP_MEMORY_SCOPE_AGENT);
            if (j < NP - 1 && tid >= 8 && tid < 16)
                M[(PR + 1) * WPR + (tid - 8)] = __hip_atomic_load(
                    &halo[(((size_t)par * NMASK + m) * NP + (j + 1)) * 16 + (tid - 8)],
                    __ATOMIC_RELAXED, __HIP_MEMORY_SCOPE_AGENT);
        }
        if (tid == 0) {
            s_bc = __hip_atomic_load(&chg[it], __ATOMIC_RELAXED,
                                     __HIP_MEMORY_SCOPE_AGENT);
            s_chg = 0;
        }
        __syncthreads();           // (E) s_bc visible
        if (s_bc == 0) break;      // uniform across all parts of this mask
    }

    // store my 128 rows back (coalesced)
    mine[j * (PR * WPR) + tid] = M[wi];
}

// ---------------- count: 16 strips/image, 256 blocks, fused final reduce ----
#define STRIPS 16
#define SROWS (HH / STRIPS)   // 32 interior rows per strip
#define SR2 (SROWS + 6)       // + 3-row halo each side
#define CBLOCKS (NB * STRIPS) // 256

// radius-3 disk dilation; strip-local r in [3, 3+SROWS)
__device__ __forceinline__ u64 dil3s(const u64* M, int r, int c) {
    u64 cm = ldh(M, r, c - 1), cc = ldh(M, r, c), cp = ldh(M, r, c + 1);
    u64 h = cc
          | (cc >> 1) | (cp << 63)
          | (cc >> 2) | (cp << 62)
          | (cc >> 3) | (cp << 61)
          | (cc << 1) | (cm >> 63)
          | (cc << 2) | (cm >> 62)
          | (cc << 3) | (cm >> 61);
    u64 um = ldh(M, r - 1, c - 1) | ldh(M, r + 1, c - 1) | ldh(M, r - 2, c - 1) | ldh(M, r + 2, c - 1);
    u64 uc = ldh(M, r - 1, c    ) | ldh(M, r + 1, c    ) | ldh(M, r - 2, c    ) | ldh(M, r + 2, c    );
    u64 up = ldh(M, r - 1, c + 1) | ldh(M, r + 1, c + 1) | ldh(M, r - 2, c + 1) | ldh(M, r + 2, c + 1);
    h |= uc
       | (uc >> 1) | (up << 63)
       | (uc >> 2) | (up << 62)
       | (uc << 1) | (um >> 63)
       | (uc << 2) | (um >> 62);
    h |= ldh(M, r - 3, c) | ldh(M, r + 3, c);
    return h;
}

__global__ __launch_bounds__(256)
void count_kernel(const u64* __restrict__ bits, int* __restrict__ cnt,
                  float* __restrict__ out) {
    __shared__ u64 P[SR2 * WPR];
    __shared__ u64 G[SR2 * WPR];
    __shared__ int acc[4];
    __shared__ int s_last;
    __shared__ int s_cnt[4 * NB];

    int b = blockIdx.x / STRIPS;
    int s = blockIdx.x % STRIPS;
    int tid = threadIdx.x;
    int r0 = s * SROWS - 3;

    const u64* sp = bits + (size_t)b * NWORDS;
    const u64* sg = bits + (size_t)(NB + b) * NWORDS;
    for (int i = tid; i < SR2 * WPR; i += 256) {
        int gr = r0 + (i >> 3);
        bool in = (gr >= 0 && gr < HH);
        int gi = gr * WPR + (i & 7);
        P[i] = in ? sp[gi] : 0ULL;
        G[i] = in ? sg[gi] : 0ULL;
    }
    if (tid < 4) acc[tid] = 0;
    __syncthreads();

    int r = (tid >> 3) + 3, c = tid & 7;
    u64 pw = P[r * WPR + c], gw = G[r * WPR + c];
    int cp  = __popcll(pw);
    int cg  = __popcll(gw);
    int tp  = __popcll(pw & dil3s(G, r, c));
    int fnh = __popcll(gw & dil3s(P, r, c));

    #pragma unroll
    for (int o = 32; o > 0; o >>= 1) {
        cp  += __shfl_down(cp, o);
        cg  += __shfl_down(cg, o);
        tp  += __shfl_down(tp, o);
        fnh += __shfl_down(fnh, o);
    }
    if ((tid & 63) == 0) {
        atomicAdd(&acc[0], cp);
        atomicAdd(&acc[1], cg);
        atomicAdd(&acc[2], tp);
        atomicAdd(&acc[3], fnh);
    }
    __syncthreads();
    if (tid < 4) atomicAdd(&cnt[b * 4 + tid], acc[tid]);

    __threadfence();
    if (tid == 0) {
        int old = atomicAdd(&cnt[4 * NB], 1);
        s_last = (old == CBLOCKS - 1);
    }
    __syncthreads();
    if (!s_last) return;
    __threadfence();
    if (tid < 4 * NB) s_cnt[tid] = atomicAdd(&cnt[tid], 0);
    __syncthreads();
    if (tid < 3) {
        float sum = 0.0f;
        for (int bb = 0; bb < NB; ++bb) {
            float TP = (float)s_cnt[bb * 4 + 2];
            float FP = (float)(s_cnt[bb * 4 + 0] - s_cnt[bb * 4 + 2]);
            float FN = (float)(s_cnt[bb * 4 + 1] - s_cnt[bb * 4 + 3]);
            float v = (tid == 0) ? TP / (TP + FP + 1e-12f)
                    : (tid == 1) ? TP / (TP + FN + 1e-12f)
                                 : TP / (TP + FP + FN + 1e-12f);
            sum += v;
        }
        out[tid] = sum * (1.0f / NB);
    }
}

extern "C" void kernel_launch(void* const* d_in, const int* in_sizes, int n_in,
                              void* d_out, int out_size, void* d_ws, size_t ws_size,
                              hipStream_t stream) {
    (void)in_sizes; (void)n_in; (void)out_size; (void)ws_size;
    const float* y_pred = (const float*)d_in[0];
    const float* y_true = (const float*)d_in[1];
    float* out = (float*)d_out;

    u64* bits = (u64*)d_ws;
    int* sync = (int*)((char*)d_ws + SYNC_OFF);
    u64* halo = (u64*)((char*)d_ws + HALO_OFF);

    hipLaunchKernelGGL(pack_kernel, dim3(2048), dim3(256), 0, stream,
                       y_pred, y_true, bits, sync);
    hipLaunchKernelGGL(skel_kernel, dim3(NMASK * NP), dim3(1024), 0, stream,
                       bits, sync, halo);
    hipLaunchKernelGGL(count_kernel, dim3(CBLOCKS), dim3(256), 0, stream,
                       bits, sync + CNT_BASE, out);
}